// Round 3
// baseline (11016.624 us; speedup 1.0000x reference)
//
#include <hip/hip_runtime.h>
#include <hip/hip_bf16.h>
#include <hip/hip_fp16.h>

// GRU B=64 S=2048 I=256 H=256, fp32 in/out.
// Phase 1: XG[m][768] = x@[Wz|Wr|Wh] + bias  (fp16 MFMA, fp32 accum)
// Phase 2: 64 WGs (one per batch row) x 768 threads (12 waves, 3/SIMD).
//          Thread (g,j) owns gate g, column j. U split: k2 in [0,96) as 96
//          packed-fp16 VGPRs (R1's 128 rode the 170-reg cap and the
//          allocator sank the loads into the loop -> L2 re-reads); k2 in
//          [96,128) staged in LDS (96KB, conflict-free b64 reads).

#define S_LEN 2048
#define BATCH 64
#define HDIM  256
#define NGATE 768
#define M_TOTAL (BATCH * S_LEN)  // 131072

#define KREG 96   // packed-pair k2 indices kept in VGPRs
#define KLDS 16   // uint2 entries per (g,j) in LDS (covers k2 96..127)

typedef _Float16 h2_t __attribute__((ext_vector_type(2)));
typedef _Float16 h8_t __attribute__((ext_vector_type(8)));
typedef float    f32x4 __attribute__((ext_vector_type(4)));

static __device__ __forceinline__ h2_t as_h2(unsigned u) {
    h2_t r; __builtin_memcpy(&r, &u, 4); return r;
}
static __device__ __forceinline__ float h2f(unsigned short s) {
    _Float16 h; __builtin_memcpy(&h, &s, 2); return (float)h;
}
static __device__ __forceinline__ unsigned short f2h(float f) {
    _Float16 h = (_Float16)f; unsigned short s; __builtin_memcpy(&s, &h, 2); return s;
}

static __device__ __forceinline__ float dot2(unsigned h, unsigned u, float acc) {
#if __has_builtin(__builtin_amdgcn_fdot2)
    return __builtin_amdgcn_fdot2(as_h2(h), as_h2(u), acc, false);
#else
    h2_t a = as_h2(h), b = as_h2(u);
    return acc + (float)a[0] * (float)b[0] + (float)a[1] * (float)b[1];
#endif
}

static __device__ __forceinline__ float sigmoid_fast(float x) {
    float e = __builtin_amdgcn_exp2f(-1.44269504088896341f * x);
    return __builtin_amdgcn_rcpf(1.0f + e);
}
static __device__ __forceinline__ float tanh_fast(float x) {
    return 2.0f * sigmoid_fast(2.0f * x) - 1.0f;
}

// ---------------- prep kernels ----------------

__global__ void k_cvt_x(const float4* __restrict__ x4, ushort4* __restrict__ xh4) {
    int i = blockIdx.x * blockDim.x + threadIdx.x;
    float4 v = x4[i];
    ushort4 o;
    o.x = f2h(v.x); o.y = f2h(v.y); o.z = f2h(v.z); o.w = f2h(v.w);
    xh4[i] = o;
}

__global__ void k_prep_w(const float* __restrict__ Wz, const float* __restrict__ Wr,
                         const float* __restrict__ Wh,
                         const float* __restrict__ bz, const float* __restrict__ br,
                         const float* __restrict__ bh,
                         const float* __restrict__ buz, const float* __restrict__ bur,
                         unsigned short* __restrict__ Wt, float* __restrict__ biascat) {
    int n = blockIdx.x;       // 0..767
    int k = threadIdx.x;      // 0..255
    int g = n >> 8, h = n & 255;
    const float* W = (g == 0) ? Wz : (g == 1) ? Wr : Wh;
    Wt[n * 256 + k] = f2h(W[k * 256 + h]);
    if (k == 0) {
        float bias = (g == 0) ? (bz[h] + buz[h]) : (g == 1) ? (br[h] + bur[h]) : bh[h];
        biascat[n] = bias;
    }
}

// pk(g,k2,j) = pack(fp16(Ug[2k2][j]), fp16(Ug[2k2+1][j]))
// k2 <  96 -> Upr[(g*96+k2)*256 + j]
// k2 >= 96 -> Upl_u[(((g*16 + (k2-96)/2)*256 + j)<<1) | (k2&1)]   (uint2 halves)
__global__ void k_prep_u(const float* __restrict__ Uz, const float* __restrict__ Ur,
                         const float* __restrict__ Uh,
                         unsigned* __restrict__ Upr, unsigned* __restrict__ Upl_u) {
    int idx = blockIdx.x * 256 + threadIdx.x;  // 0..98303
    int j  = idx & 255;
    int k2 = (idx >> 8) & 127;
    int g  = idx >> 15;
    const float* U = (g == 0) ? Uz : (g == 1) ? Ur : Uh;
    unsigned lo = f2h(U[(2 * k2) * 256 + j]);
    unsigned hi = f2h(U[(2 * k2 + 1) * 256 + j]);
    unsigned pk = lo | (hi << 16);
    if (k2 < KREG) {
        Upr[(g * KREG + k2) * 256 + j] = pk;
    } else {
        int q = (k2 - KREG) >> 1;
        Upl_u[(((g * KLDS + q) * 256 + j) << 1) | (k2 & 1)] = pk;
    }
}

// ---------------- phase 1: input GEMM ----------------

#define LDT 264  // 256 + 8 halves per LDS row

__global__ __launch_bounds__(256) void k_gemm_x(const unsigned short* __restrict__ Xh,
                                                const unsigned short* __restrict__ Wt,
                                                const float* __restrict__ biascat,
                                                unsigned short* __restrict__ XG) {
    __shared__ unsigned short As[128 * LDT];
    __shared__ unsigned short Bs[128 * LDT];
    int tid = threadIdx.x;
    int m0 = blockIdx.x * 128;
    int n0 = blockIdx.y * 128;

    {
        const unsigned short* ga = Xh + (size_t)m0 * 256;
        const unsigned short* gb = Wt + (size_t)n0 * 256;
#pragma unroll
        for (int i = 0; i < 16; i++) {
            int chunk = tid + i * 256;
            int row = chunk >> 5;
            int c8  = (chunk & 31) * 8;
            uint4 va = *(const uint4*)(ga + row * 256 + c8);
            *(uint4*)(As + row * LDT + c8) = va;
            uint4 vb = *(const uint4*)(gb + row * 256 + c8);
            *(uint4*)(Bs + row * LDT + c8) = vb;
        }
    }
    __syncthreads();

    int lane = tid & 63, wv = tid >> 6;
    int mw = (wv & 1) * 64, nw = (wv >> 1) * 64;
    int lr = lane & 15, lg = lane >> 4;

    f32x4 acc[4][4] = {};
#pragma unroll
    for (int k = 0; k < 8; k++) {
        h8_t a[4], b[4];
#pragma unroll
        for (int i = 0; i < 4; i++)
            a[i] = *(const h8_t*)(As + (mw + i * 16 + lr) * LDT + k * 32 + lg * 8);
#pragma unroll
        for (int jj = 0; jj < 4; jj++)
            b[jj] = *(const h8_t*)(Bs + (nw + jj * 16 + lr) * LDT + k * 32 + lg * 8);
#pragma unroll
        for (int i = 0; i < 4; i++)
#pragma unroll
            for (int jj = 0; jj < 4; jj++)
                acc[i][jj] = __builtin_amdgcn_mfma_f32_16x16x32_f16(a[i], b[jj], acc[i][jj], 0, 0, 0);
    }

#pragma unroll
    for (int jj = 0; jj < 4; jj++) {
        int gcol = n0 + nw + jj * 16 + lr;
        float bias = biascat[gcol];
#pragma unroll
        for (int i = 0; i < 4; i++) {
            int grow = m0 + mw + i * 16 + lg * 4;
#pragma unroll
            for (int r = 0; r < 4; r++) {
                XG[(size_t)(grow + r) * NGATE + gcol] = f2h(acc[i][jj][r] + bias);
            }
        }
    }
}

// ---------------- phase 2: recurrence ----------------

__global__ __launch_bounds__(768, 3) void k_gru(const unsigned* __restrict__ Upr,
                                                const uint2* __restrict__ Upl,
                                                const unsigned short* __restrict__ XG,
                                                const float* __restrict__ buh,
                                                float* __restrict__ out) {
    __shared__ __align__(16) unsigned short hb[2][256];
    __shared__ float part[3][256];
    __shared__ uint2 uld[3 * KLDS * 256];  // 96KB
    int tid = threadIdx.x;
    int j = tid & 255, g = tid >> 8;
    int b = blockIdx.x;

    // stage LDS-resident U slice (coalesced)
#pragma unroll
    for (int i = 0; i < 16; i++) {
        int e = tid + i * 768;
        uld[e] = Upl[e];
    }

    unsigned u[KREG];
    {
        const unsigned* base = Upr + g * (KREG * 256) + j;
#pragma unroll
        for (int k = 0; k < KREG; k++) u[k] = base[k * 256];
    }
    float bias = (g == 2) ? buh[j] : 0.0f;

    const unsigned short* xg  = XG + (size_t)b * S_LEN * NGATE + g * 256 + j;
    const unsigned short* xgh = XG + (size_t)b * S_LEN * NGATE + 512 + j;
    float* ob = out + (size_t)b * S_LEN * HDIM + j;

    if (g == 0) { hb[0][j] = 0; hb[1][j] = 0; }

    unsigned short px  = (g != 2) ? xg[0] : (unsigned short)0;
    unsigned short pxh = (g == 0) ? xgh[0] : (unsigned short)0;
    float hm = 0.0f;  // fp32 master h (group 0 only)
    __syncthreads();

    const uint2* up = uld + g * (KLDS * 256) + j;

    for (int t = 0; t < S_LEN; ++t) {
        int cur = t & 1;
        float xc   = (g != 2) ? h2f(px)  : 0.0f;
        float xh_v = h2f(pxh);
        int tn = (t + 1 < S_LEN) ? (t + 1) : t;
        if (g != 2) px  = xg[(size_t)tn * NGATE];
        if (g == 0) pxh = xgh[(size_t)tn * NGATE];

        float a0 = bias, a1 = 0.f, a2 = 0.f, a3 = 0.f;
        const uint4* hrow4 = (const uint4*)hb[cur];
#pragma unroll
        for (int k8 = 0; k8 < KREG / 4; k8++) {
            uint4 hv = hrow4[k8];
            int k = k8 * 4;
            a0 = dot2(hv.x, u[k + 0], a0);
            a1 = dot2(hv.y, u[k + 1], a1);
            a2 = dot2(hv.z, u[k + 2], a2);
            a3 = dot2(hv.w, u[k + 3], a3);
        }
        const uint2* hrow2 = (const uint2*)hb[cur];
#pragma unroll
        for (int q = 0; q < KLDS; q++) {
            uint2 uv = up[q * 256];
            uint2 hv = hrow2[KREG / 2 + q];
            a0 = dot2(hv.x, uv.x, a0);
            a1 = dot2(hv.y, uv.y, a1);
        }
        part[g][j] = (a0 + a2) + (a1 + a3) + xc;
        __syncthreads();

        if (g == 0) {
            float z = sigmoid_fast(part[0][j]);
            float r = sigmoid_fast(part[1][j]);
            float cand = tanh_fast(xh_v + r * part[2][j]);
            hm = (1.0f - z) * hm + z * cand;
            ob[(size_t)t * HDIM] = hm;
            hb[cur ^ 1][j] = f2h(hm);
        }
        __syncthreads();
    }
}

// ---------------- launch ----------------

extern "C" void kernel_launch(void* const* d_in, const int* in_sizes, int n_in,
                              void* d_out, int out_size, void* d_ws, size_t ws_size,
                              hipStream_t stream) {
    const float* x   = (const float*)d_in[0];
    const float* Wz  = (const float*)d_in[1];
    const float* bz  = (const float*)d_in[2];
    const float* Wr  = (const float*)d_in[3];
    const float* br  = (const float*)d_in[4];
    const float* Wh  = (const float*)d_in[5];
    const float* bh  = (const float*)d_in[6];
    const float* Uz  = (const float*)d_in[7];
    const float* buz = (const float*)d_in[8];
    const float* Ur  = (const float*)d_in[9];
    const float* bur = (const float*)d_in[10];
    const float* Uh  = (const float*)d_in[11];
    const float* buh = (const float*)d_in[12];

    char* ws = (char*)d_ws;
    // layout: Xh 64MiB | XG 192MiB | Wt 384KiB | Upr 288KiB | Upl 96KiB | biascat 3KiB
    unsigned short* Xh = (unsigned short*)(ws);
    unsigned short* XG = (unsigned short*)(ws + 67108864);
    unsigned short* Wt = (unsigned short*)(ws + 268435456);
    unsigned*       Upr = (unsigned*)(ws + 268828672);
    unsigned*       Upl = (unsigned*)(ws + 269123584);
    float*          biascat = (float*)(ws + 269221888);

    k_cvt_x<<<32768, 256, 0, stream>>>((const float4*)x, (ushort4*)Xh);
    k_prep_w<<<768, 256, 0, stream>>>(Wz, Wr, Wh, bz, br, bh, buz, bur, Wt, biascat);
    k_prep_u<<<384, 256, 0, stream>>>(Uz, Ur, Uh, Upr, Upl);

    dim3 g1(M_TOTAL / 128, NGATE / 128);
    k_gemm_x<<<g1, 256, 0, stream>>>(Xh, Wt, biascat, XG);

    k_gru<<<BATCH, 768, 0, stream>>>(Upr, (const uint2*)Upl, XG, buh, (float*)d_out);
}

// Round 4
// 2348.984 us; speedup vs baseline: 4.6900x; 4.6900x over previous
//
#include <hip/hip_runtime.h>
#include <hip/hip_bf16.h>
#include <hip/hip_fp16.h>

// GRU B=64 S=2048 I=256 H=256, fp32 in/out.
// Phase 1: XG[m][768] = x@[Wz|Wr|Wh] + bias  (fp16 MFMA, fp32 accum)
// Phase 2: 64 WGs x 512 threads, waves_per_eu pinned to (2,2):
//   R1/R2 post-mortem: VGPR_Count=84 = 512/6 -> allocator self-targeted
//   6 waves/EU and rematerialized ALL U loads into the t-loop (L2 reads
//   every step). Fix = amdgpu_waves_per_eu(2,2) -> 256-reg budget.
//   Thread (j=tid>>1, s=tid&1) owns all 3 gates of column j, K-half s:
//   192 packed-fp16 U regs. Pair partials combined via __shfl_xor(1)
//   (adjacent lanes, DPP) -> no LDS combine, 1 barrier/step.

#define S_LEN 2048
#define BATCH 64
#define HDIM  256
#define NGATE 768
#define M_TOTAL (BATCH * S_LEN)  // 131072

typedef _Float16 h2_t __attribute__((ext_vector_type(2)));
typedef _Float16 h8_t __attribute__((ext_vector_type(8)));
typedef float    f32x4 __attribute__((ext_vector_type(4)));

static __device__ __forceinline__ h2_t as_h2(unsigned u) {
    h2_t r; __builtin_memcpy(&r, &u, 4); return r;
}
static __device__ __forceinline__ float h2f(unsigned short s) {
    _Float16 h; __builtin_memcpy(&h, &s, 2); return (float)h;
}
static __device__ __forceinline__ unsigned short f2h(float f) {
    _Float16 h = (_Float16)f; unsigned short s; __builtin_memcpy(&s, &h, 2); return s;
}

static __device__ __forceinline__ float dot2(unsigned h, unsigned u, float acc) {
#if __has_builtin(__builtin_amdgcn_fdot2)
    return __builtin_amdgcn_fdot2(as_h2(h), as_h2(u), acc, false);
#else
    h2_t a = as_h2(h), b = as_h2(u);
    return acc + (float)a[0] * (float)b[0] + (float)a[1] * (float)b[1];
#endif
}

static __device__ __forceinline__ float sigmoid_fast(float x) {
    float e = __builtin_amdgcn_exp2f(-1.44269504088896341f * x);
    return __builtin_amdgcn_rcpf(1.0f + e);
}
static __device__ __forceinline__ float tanh_fast(float x) {
    return 2.0f * sigmoid_fast(2.0f * x) - 1.0f;
}

// ---------------- prep kernels ----------------

__global__ void k_cvt_x(const float4* __restrict__ x4, ushort4* __restrict__ xh4) {
    int i = blockIdx.x * blockDim.x + threadIdx.x;
    float4 v = x4[i];
    ushort4 o;
    o.x = f2h(v.x); o.y = f2h(v.y); o.z = f2h(v.z); o.w = f2h(v.w);
    xh4[i] = o;
}

__global__ void k_prep_w(const float* __restrict__ Wz, const float* __restrict__ Wr,
                         const float* __restrict__ Wh,
                         const float* __restrict__ bz, const float* __restrict__ br,
                         const float* __restrict__ bh,
                         const float* __restrict__ buz, const float* __restrict__ bur,
                         unsigned short* __restrict__ Wt, float* __restrict__ biascat) {
    int n = blockIdx.x;       // 0..767
    int k = threadIdx.x;      // 0..255
    int g = n >> 8, h = n & 255;
    const float* W = (g == 0) ? Wz : (g == 1) ? Wr : Wh;
    Wt[n * 256 + k] = f2h(W[k * 256 + h]);
    if (k == 0) {
        float bias = (g == 0) ? (bz[h] + buz[h]) : (g == 1) ? (br[h] + bur[h]) : bh[h];
        biascat[n] = bias;
    }
}

// Upk[(g*128+k2)*256 + j] = pack(fp16(Ug[2k2][j]), fp16(Ug[2k2+1][j]))
__global__ void k_prep_u(const float* __restrict__ Uz, const float* __restrict__ Ur,
                         const float* __restrict__ Uh, unsigned* __restrict__ Upk) {
    int idx = blockIdx.x * 256 + threadIdx.x;  // 0..98303
    int j  = idx & 255;
    int k2 = (idx >> 8) & 127;
    int g  = idx >> 15;
    const float* U = (g == 0) ? Uz : (g == 1) ? Ur : Uh;
    unsigned lo = f2h(U[(2 * k2) * 256 + j]);
    unsigned hi = f2h(U[(2 * k2 + 1) * 256 + j]);
    Upk[idx] = lo | (hi << 16);
}

// ---------------- phase 1: input GEMM ----------------

#define LDT 264  // 256 + 8 halves per LDS row

__global__ __launch_bounds__(256) void k_gemm_x(const unsigned short* __restrict__ Xh,
                                                const unsigned short* __restrict__ Wt,
                                                const float* __restrict__ biascat,
                                                unsigned short* __restrict__ XG) {
    __shared__ unsigned short As[128 * LDT];
    __shared__ unsigned short Bs[128 * LDT];
    int tid = threadIdx.x;
    int m0 = blockIdx.x * 128;
    int n0 = blockIdx.y * 128;

    {
        const unsigned short* ga = Xh + (size_t)m0 * 256;
        const unsigned short* gb = Wt + (size_t)n0 * 256;
#pragma unroll
        for (int i = 0; i < 16; i++) {
            int chunk = tid + i * 256;
            int row = chunk >> 5;
            int c8  = (chunk & 31) * 8;
            uint4 va = *(const uint4*)(ga + row * 256 + c8);
            *(uint4*)(As + row * LDT + c8) = va;
            uint4 vb = *(const uint4*)(gb + row * 256 + c8);
            *(uint4*)(Bs + row * LDT + c8) = vb;
        }
    }
    __syncthreads();

    int lane = tid & 63, wv = tid >> 6;
    int mw = (wv & 1) * 64, nw = (wv >> 1) * 64;
    int lr = lane & 15, lg = lane >> 4;

    f32x4 acc[4][4] = {};
#pragma unroll
    for (int k = 0; k < 8; k++) {
        h8_t a[4], b[4];
#pragma unroll
        for (int i = 0; i < 4; i++)
            a[i] = *(const h8_t*)(As + (mw + i * 16 + lr) * LDT + k * 32 + lg * 8);
#pragma unroll
        for (int jj = 0; jj < 4; jj++)
            b[jj] = *(const h8_t*)(Bs + (nw + jj * 16 + lr) * LDT + k * 32 + lg * 8);
#pragma unroll
        for (int i = 0; i < 4; i++)
#pragma unroll
            for (int jj = 0; jj < 4; jj++)
                acc[i][jj] = __builtin_amdgcn_mfma_f32_16x16x32_f16(a[i], b[jj], acc[i][jj], 0, 0, 0);
    }

#pragma unroll
    for (int jj = 0; jj < 4; jj++) {
        int gcol = n0 + nw + jj * 16 + lr;
        float bias = biascat[gcol];
#pragma unroll
        for (int i = 0; i < 4; i++) {
            int grow = m0 + mw + i * 16 + lg * 4;
#pragma unroll
            for (int r = 0; r < 4; r++) {
                XG[(size_t)(grow + r) * NGATE + gcol] = f2h(acc[i][jj][r] + bias);
            }
        }
    }
}

// ---------------- phase 2: recurrence ----------------

__global__ __launch_bounds__(512) __attribute__((amdgpu_waves_per_eu(2, 2)))
void k_gru(const unsigned* __restrict__ Upk,
           const unsigned short* __restrict__ XG,
           const float* __restrict__ buh,
           float* __restrict__ out) {
    __shared__ __align__(16) unsigned short hb[2][256];
    int tid = threadIdx.x;
    int j = tid >> 1, s = tid & 1;
    int b = blockIdx.x;

    // preamble: 192 packed-fp16 U registers per thread
    unsigned uz[64], ur[64], uh[64];
    {
        const unsigned* base = Upk + (size_t)(s * 64) * 256 + j;
#pragma unroll
        for (int k = 0; k < 64; k++) uz[k] = base[k * 256];
#pragma unroll
        for (int k = 0; k < 64; k++) ur[k] = base[(128 + k) * 256];
#pragma unroll
        for (int k = 0; k < 64; k++) uh[k] = base[(256 + k) * 256];
    }
    // pin all 192 values: asm-defined values cannot be rematerialized
#pragma unroll
    for (int k = 0; k < 64; k++) {
        asm volatile("" : "+v"(uz[k]), "+v"(ur[k]), "+v"(uh[k]));
    }

    float buh_j = buh[j];
    if (tid < 256) { hb[0][tid] = 0; hb[1][tid] = 0; }

    const unsigned short* xgp = XG + (size_t)b * S_LEN * NGATE + j;
    float* ob = out + (size_t)b * S_LEN * HDIM + j;

    // prefetch t=0 gate inputs (lane pairs load same address - HW merges)
    unsigned short pz = xgp[0], pr = xgp[256], ph = xgp[512];
    float hm = 0.0f;  // fp32 master h (kept identically in both lanes)
    __syncthreads();

    for (int t = 0; t < S_LEN; ++t) {
        int cur = t & 1;
        float xz = h2f(pz), xr = h2f(pr), xh = h2f(ph);
        const unsigned short* nx = xgp + (size_t)((t + 1 < S_LEN) ? t + 1 : t) * NGATE;
        pz = nx[0]; pr = nx[256]; ph = nx[512];

        float az0 = 0.f, az1 = 0.f, ar0 = 0.f, ar1 = 0.f, ah0 = 0.f, ah1 = 0.f;
        const uint4* hrow = (const uint4*)hb[cur] + s * 16;
#pragma unroll
        for (int c = 0; c < 16; c++) {
            uint4 hv = hrow[c];
            int k = c * 4;
            az0 = dot2(hv.x, uz[k + 0], az0); az1 = dot2(hv.y, uz[k + 1], az1);
            ar0 = dot2(hv.x, ur[k + 0], ar0); ar1 = dot2(hv.y, ur[k + 1], ar1);
            ah0 = dot2(hv.x, uh[k + 0], ah0); ah1 = dot2(hv.y, uh[k + 1], ah1);
            az0 = dot2(hv.z, uz[k + 2], az0); az1 = dot2(hv.w, uz[k + 3], az1);
            ar0 = dot2(hv.z, ur[k + 2], ar0); ar1 = dot2(hv.w, ur[k + 3], ar1);
            ah0 = dot2(hv.z, uh[k + 2], ah0); ah1 = dot2(hv.w, uh[k + 3], ah1);
        }
        // combine K-halves across the adjacent-lane pair (DPP swap)
        float sz = az0 + az1, sr = ar0 + ar1, sh = ah0 + ah1;
        sz += __shfl_xor(sz, 1, 64);
        sr += __shfl_xor(sr, 1, 64);
        sh += __shfl_xor(sh, 1, 64);

        float z = sigmoid_fast(xz + sz);
        float r = sigmoid_fast(xr + sr);
        float cand = tanh_fast(xh + r * (sh + buh_j));
        hm = (1.0f - z) * hm + z * cand;

        if (s == 0) {
            ob[(size_t)t * HDIM] = hm;
            hb[cur ^ 1][j] = f2h(hm);
        }
        __syncthreads();
    }
}

// ---------------- launch ----------------

extern "C" void kernel_launch(void* const* d_in, const int* in_sizes, int n_in,
                              void* d_out, int out_size, void* d_ws, size_t ws_size,
                              hipStream_t stream) {
    const float* x   = (const float*)d_in[0];
    const float* Wz  = (const float*)d_in[1];
    const float* bz  = (const float*)d_in[2];
    const float* Wr  = (const float*)d_in[3];
    const float* br  = (const float*)d_in[4];
    const float* Wh  = (const float*)d_in[5];
    const float* bh  = (const float*)d_in[6];
    const float* Uz  = (const float*)d_in[7];
    const float* buz = (const float*)d_in[8];
    const float* Ur  = (const float*)d_in[9];
    const float* bur = (const float*)d_in[10];
    const float* Uh  = (const float*)d_in[11];
    const float* buh = (const float*)d_in[12];

    char* ws = (char*)d_ws;
    // layout: Xh 64MiB | XG 192MiB | Wt 384KiB | Upk 384KiB | biascat 3KiB
    unsigned short* Xh = (unsigned short*)(ws);
    unsigned short* XG = (unsigned short*)(ws + 67108864);
    unsigned short* Wt = (unsigned short*)(ws + 268435456);
    unsigned*       Upk = (unsigned*)(ws + 268828672);
    float*          biascat = (float*)(ws + 269221888);

    k_cvt_x<<<32768, 256, 0, stream>>>((const float4*)x, (ushort4*)Xh);
    k_prep_w<<<768, 256, 0, stream>>>(Wz, Wr, Wh, bz, br, bh, buz, bur, Wt, biascat);
    k_prep_u<<<384, 256, 0, stream>>>(Uz, Ur, Uh, Upk);

    dim3 g1(M_TOTAL / 128, NGATE / 128);
    k_gemm_x<<<g1, 256, 0, stream>>>(Xh, Wt, biascat, XG);

    k_gru<<<BATCH, 512, 0, stream>>>(Upk, XG, buh, (float*)d_out);
}